// Round 2
// baseline (8119.807 us; speedup 1.0000x reference)
//
#include <hip/hip_runtime.h>

// LSTM (bias-free) unrolled over T=512, B=512, D=8, H=256, with per-step Linear(H,2).
// Strategy: batch-split persistent blocks (no grid sync). 128 blocks x 512 threads.
// Each block owns 4 batch rows; thread (u, rp) owns hidden unit u for rows {4b+2rp, 4b+2rp+1}.
// W_hh pre-transposed into ws as PW[k][u] = float4(i,f,g,o) -> one coalesced dwordx4 per k.
// h lives in 4KB LDS (float4 per unit = 4 rows), c in registers. 2 barriers/step.
// Balance: n blocks -> L2 0.029n us/step vs compute 450/n us/step; n=128 optimal.

#define T_STEPS 512
#define B_ROWS  512
#define D_IN    8
#define HID     256

#define PW_FLOATS   (4*HID*HID)      // 262144 (1 MB)
#define PWIH_FLOATS (4*HID*D_IN)     // 8192   (32 KB)
#define WS_FLOATS_NEEDED (PW_FLOATS + PWIH_FLOATS)

// Build PW[k][u][g] = W_hh[g*H+u][k]  and  PWih[d][u][g] = W_ih[g*H+u][d]
__global__ void prep_kernel(const float* __restrict__ Wih,
                            const float* __restrict__ Whh,
                            float* __restrict__ PW,
                            float* __restrict__ PWih) {
  int p = blockIdx.x * 256 + threadIdx.x;
  if (p < PW_FLOATS) {
    int g = p & 3, u = (p >> 2) & (HID - 1), k = p >> 10;
    PW[p] = Whh[(g * HID + u) * HID + k];
  } else {
    int q = p - PW_FLOATS;
    if (q < PWIH_FLOATS) {
      int g = q & 3, u = (q >> 2) & (HID - 1), d = q >> 10;
      PWih[q] = Wih[(g * HID + u) * D_IN + d];
    }
  }
}

__device__ __forceinline__ float sigmoidf_(float x) {
  return 1.f / (1.f + expf(-x));
}
__device__ __forceinline__ float tanhf_(float x) {
  // 1 - 2/(e^{2x}+1): exact limits at +/-inf, ~1-2 ulp elsewhere
  float e = expf(2.f * x);
  return 1.f - 2.f / (e + 1.f);
}

template <bool DIRECT>
__global__ __launch_bounds__(512)
void lstm_kernel(const float* __restrict__ hist,
                 const float* __restrict__ Wih,
                 const float* __restrict__ Whh,
                 const float* __restrict__ Wout,
                 const float* __restrict__ bout,
                 const float4* __restrict__ PW,
                 const float4* __restrict__ PWih,
                 float* __restrict__ out) {
  __shared__ float4 h4[HID];      // h for this block's 4 rows, indexed by hidden unit
  __shared__ float  wo[2 * HID];  // W_out staged

  const int t    = threadIdx.x;
  const int u    = t & (HID - 1);
  const int rp   = t >> 8;                    // row-pair 0/1
  const int row0 = blockIdx.x * 4 + rp * 2;   // this thread's rows: row0, row0+1

  wo[t] = Wout[t];                            // 512 threads load 2*256 floats
  if (t < HID) h4[t] = make_float4(0.f, 0.f, 0.f, 0.f);
  float c0 = 0.f, c1 = 0.f;
  float h0n = 0.f, h1n = 0.f;
  const float b0 = bout[0], b1 = bout[1];
  __syncthreads();

  // x rows as float4 pairs: hist row is 16KB-aligned off base, step*8 floats = 32B-aligned
  const float4* __restrict__ x4r0 = (const float4*)(hist + (long)row0 * T_STEPS * D_IN);
  const float4* __restrict__ x4r1 = (const float4*)(hist + (long)(row0 + 1) * T_STEPS * D_IN);
  const float2* __restrict__ h2p = (const float2*)h4;

  for (int step = 0; step < T_STEPS; ++step) {
    float ai0 = 0.f, af0 = 0.f, ag0 = 0.f, ao0 = 0.f;
    float ai1 = 0.f, af1 = 0.f, ag1 = 0.f, ao1 = 0.f;

    // ---- x @ W_ih.T (D=8): 4 vector loads, broadcast across lanes (L1-hit) ----
    {
      float4 xa0 = x4r0[step * 2], xb0 = x4r0[step * 2 + 1];
      float4 xa1 = x4r1[step * 2], xb1 = x4r1[step * 2 + 1];
      float xv0[D_IN] = {xa0.x, xa0.y, xa0.z, xa0.w, xb0.x, xb0.y, xb0.z, xb0.w};
      float xv1[D_IN] = {xa1.x, xa1.y, xa1.z, xa1.w, xb1.x, xb1.y, xb1.z, xb1.w};
      #pragma unroll
      for (int d = 0; d < D_IN; ++d) {
        float4 w;
        if (DIRECT) {
          w.x = Wih[(0 * HID + u) * D_IN + d];
          w.y = Wih[(1 * HID + u) * D_IN + d];
          w.z = Wih[(2 * HID + u) * D_IN + d];
          w.w = Wih[(3 * HID + u) * D_IN + d];
        } else {
          w = PWih[d * HID + u];
        }
        ai0 = fmaf(w.x, xv0[d], ai0); af0 = fmaf(w.y, xv0[d], af0);
        ag0 = fmaf(w.z, xv0[d], ag0); ao0 = fmaf(w.w, xv0[d], ao0);
        ai1 = fmaf(w.x, xv1[d], ai1); af1 = fmaf(w.y, xv1[d], af1);
        ag1 = fmaf(w.z, xv1[d], ag1); ao1 = fmaf(w.w, xv1[d], ao1);
      }
    }

    // ---- h @ W_hh.T : 1 coalesced dwordx4 (weights) + 1 ds_read_b64 (h, broadcast) per k ----
    #pragma unroll 8
    for (int k = 0; k < HID; ++k) {
      float4 w;
      if (DIRECT) {
        w.x = Whh[(0 * HID + u) * HID + k];
        w.y = Whh[(1 * HID + u) * HID + k];
        w.z = Whh[(2 * HID + u) * HID + k];
        w.w = Whh[(3 * HID + u) * HID + k];
      } else {
        w = PW[k * HID + u];
      }
      float2 hh = h2p[k * 2 + rp];
      ai0 = fmaf(w.x, hh.x, ai0); af0 = fmaf(w.y, hh.x, af0);
      ag0 = fmaf(w.z, hh.x, ag0); ao0 = fmaf(w.w, hh.x, ao0);
      ai1 = fmaf(w.x, hh.y, ai1); af1 = fmaf(w.y, hh.y, af1);
      ag1 = fmaf(w.z, hh.y, ag1); ao1 = fmaf(w.w, hh.y, ao1);
    }

    // ---- gate nonlinearities + state update (c stays in registers) ----
    {
      float i0 = sigmoidf_(ai0), f0 = sigmoidf_(af0), g0 = tanhf_(ag0), o0 = sigmoidf_(ao0);
      float i1 = sigmoidf_(ai1), f1 = sigmoidf_(af1), g1 = tanhf_(ag1), o1 = sigmoidf_(ao1);
      c0 = fmaf(f0, c0, i0 * g0);
      c1 = fmaf(f1, c1, i1 * g1);
      h0n = o0 * tanhf_(c0);
      h1n = o1 * tanhf_(c1);
    }

    __syncthreads();   // all reads of h(step) complete
    ((float2*)h4)[u * 2 + rp] = make_float2(h0n, h1n);
    __syncthreads();   // h(step+1) visible

    // ---- logits: 8 waves -> 8 (row, logit) combos, shuffle-reduce over 64 lanes ----
    {
      const int wv   = t >> 6;
      const int lane = t & 63;
      const int r    = wv >> 1;   // 0..3 row within block tile
      const int lg   = wv & 1;
      float partial = 0.f;
      #pragma unroll
      for (int m = 0; m < 4; ++m) {
        int k = lane + 64 * m;
        float4 hv = h4[k];
        float hval = (r == 0) ? hv.x : (r == 1) ? hv.y : (r == 2) ? hv.z : hv.w;
        partial = fmaf(hval, wo[lg * HID + k], partial);
      }
      #pragma unroll
      for (int off = 32; off > 0; off >>= 1)
        partial += __shfl_down(partial, off, 64);
      if (lane == 0) {
        long row = (long)blockIdx.x * 4 + r;
        out[(row * T_STEPS + step) * 2 + lg] = partial + (lg ? b1 : b0);
      }
    }
  }

  // ---- final h_T, c_T (from registers; coalesced over u) ----
  const long HOFF = (long)B_ROWS * T_STEPS * 2;           // 524288
  const long COFF = HOFF + (long)B_ROWS * HID;            // 655360
  out[HOFF + (long)row0 * HID + u]       = h0n;
  out[HOFF + (long)(row0 + 1) * HID + u] = h1n;
  out[COFF + (long)row0 * HID + u]       = c0;
  out[COFF + (long)(row0 + 1) * HID + u] = c1;
}

extern "C" void kernel_launch(void* const* d_in, const int* in_sizes, int n_in,
                              void* d_out, int out_size, void* d_ws, size_t ws_size,
                              hipStream_t stream) {
  const float* hist = (const float*)d_in[0];
  const float* Wih  = (const float*)d_in[1];
  const float* Whh  = (const float*)d_in[2];
  const float* Wout = (const float*)d_in[3];
  const float* bout = (const float*)d_in[4];
  float* out = (float*)d_out;

  if (ws_size >= WS_FLOATS_NEEDED * sizeof(float)) {
    float* PW   = (float*)d_ws;
    float* PWih = PW + PW_FLOATS;
    // 262144 + 8192 elements / 256 = 1056 blocks exactly
    prep_kernel<<<1056, 256, 0, stream>>>(Wih, Whh, PW, PWih);
    lstm_kernel<false><<<B_ROWS / 4, 512, 0, stream>>>(
        hist, Wih, Whh, Wout, bout, (const float4*)PW, (const float4*)PWih, out);
  } else {
    // workspace too small: correct (slow) fallback reading weights in native layout
    lstm_kernel<true><<<B_ROWS / 4, 512, 0, stream>>>(
        hist, Wih, Whh, Wout, bout, nullptr, nullptr, out);
  }
}

// Round 7
// 6651.587 us; speedup vs baseline: 1.2207x; 1.2207x over previous
//
#include <hip/hip_runtime.h>

// LSTM (bias-free) T=512, B=512, D=8, H=256 + per-step Linear(H,2).
// R7 (= R6 resubmit, re-audited; never ran): 128 blocks x 1024 threads (k-split x2,
// latency hiding) + fp16-PACKED W_hh stream converted in-register to fp32 FMA
// (weights-only quantization; h stays fp32). Per-CU weight bytes 1MB -> 512KB/step.
// Thread (u, rp, ks): unit u, row-pair rp, k-half ks. Partials reduced via LDS
// [ks][g][r][u]; c,h owned by (u, row=2rp+ks). 2 barriers/step.

#define T_STEPS 512
#define B_ROWS  512
#define D_IN    8
#define HID     256

typedef _Float16 half2_t __attribute__((ext_vector_type(2)));

#define PW2_ENTRIES (128 * HID)            // 32768 uint4 (16B each) = 512 KB
#define PWIH_FLOATS (4 * HID * D_IN)       // 8192 floats = 32 KB
#define WS_BYTES_NEEDED ((size_t)PW2_ENTRIES * 16 + (size_t)PWIH_FLOATS * 4)

// PW2[k2*HID+u] = uint4{ half2(Whh[g*H+u][2k2], Whh[g*H+u][2k2+1]) : g=0..3 }
// PWih[d*1024 + u*4 + g] = Wih[g*H+u][d]   (fp32, tiny)
__global__ void prep_kernel(const float* __restrict__ Wih,
                            const float* __restrict__ Whh,
                            uint4* __restrict__ PW2,
                            float* __restrict__ PWih) {
  int p = blockIdx.x * 256 + threadIdx.x;
  if (p < PW2_ENTRIES) {
    int u = p & (HID - 1), k2 = p >> 8;
    unsigned int g[4];
    #pragma unroll
    for (int gi = 0; gi < 4; ++gi) {
      float lo = Whh[(gi * HID + u) * HID + 2 * k2];
      float hi = Whh[(gi * HID + u) * HID + 2 * k2 + 1];
      half2_t hv;
      hv[0] = (_Float16)lo;
      hv[1] = (_Float16)hi;
      g[gi] = __builtin_bit_cast(unsigned int, hv);
    }
    PW2[p] = make_uint4(g[0], g[1], g[2], g[3]);
  } else {
    int q = p - PW2_ENTRIES;
    if (q < PWIH_FLOATS) {
      int gg = q & 3, u = (q >> 2) & (HID - 1), d = q >> 10;
      PWih[q] = Wih[(gg * HID + u) * D_IN + d];
    }
  }
}

__device__ __forceinline__ float sigmoidf_(float x) {
  return 1.f / (1.f + expf(-x));
}
__device__ __forceinline__ float tanhf_(float x) {
  float e = expf(2.f * x);
  return 1.f - 2.f / (e + 1.f);
}

template <bool DIRECT>
__global__ __launch_bounds__(1024, 4)
void lstm_kernel(const float* __restrict__ hist,
                 const float* __restrict__ Wih,
                 const float* __restrict__ Whh,
                 const float* __restrict__ Wout,
                 const float* __restrict__ bout,
                 const uint4* __restrict__ PW2,
                 const float4* __restrict__ PWih,
                 float* __restrict__ out) {
  __shared__ float4 h4[HID];              // fp32 h, [u]{rows 0..3}, 4KB
  __shared__ float  wo[2 * HID];          // W_out staged, 2KB
  __shared__ float  part[2][4][4][HID];   // [ks][gate][row][u] partials, 32KB

  const int t  = threadIdx.x;
  const int u  = t & (HID - 1);
  const int rp = (t >> 8) & 1;            // row-pair: rows 2rp, 2rp+1
  const int ks = t >> 9;                  // k-half
  const int rowR = 2 * rp + ks;           // OWNED (row,u) post-reduce

  if (t < 2 * HID) wo[t] = Wout[t];
  if (t < HID) h4[t] = make_float4(0.f, 0.f, 0.f, 0.f);
  float c_reg = 0.f, h_reg = 0.f;
  const float b0 = bout[0], b1 = bout[1];
  __syncthreads();

  const int row0 = blockIdx.x * 4 + rp * 2;
  const float4* __restrict__ x4r0 = (const float4*)(hist + (long)row0 * T_STEPS * D_IN);
  const float4* __restrict__ x4r1 = (const float4*)(hist + (long)(row0 + 1) * T_STEPS * D_IN);
  const float2* __restrict__ h2p = (const float2*)h4;   // h2p[k*2+rp] = {h[2rp], h[2rp+1]} of unit k
  const uint4* __restrict__ pwk = DIRECT ? nullptr : (PW2 + (size_t)ks * 64 * HID + u);
  const int hb = 256 * ks + rp;           // base for h2p reads in the k-loop

  for (int step = 0; step < T_STEPS; ++step) {
    float ai0 = 0.f, af0 = 0.f, ag0 = 0.f, ao0 = 0.f;
    float ai1 = 0.f, af1 = 0.f, ag1 = 0.f, ao1 = 0.f;

    // ---- x @ W_ih.T (D=8, fp32): ks==0 threads only ----
    if (ks == 0) {
      float4 xa0 = x4r0[step * 2], xb0 = x4r0[step * 2 + 1];
      float4 xa1 = x4r1[step * 2], xb1 = x4r1[step * 2 + 1];
      float xv0[D_IN] = {xa0.x, xa0.y, xa0.z, xa0.w, xb0.x, xb0.y, xb0.z, xb0.w};
      float xv1[D_IN] = {xa1.x, xa1.y, xa1.z, xa1.w, xb1.x, xb1.y, xb1.z, xb1.w};
      #pragma unroll
      for (int d = 0; d < D_IN; ++d) {
        float4 w;
        if (DIRECT) {
          w.x = Wih[(0 * HID + u) * D_IN + d];
          w.y = Wih[(1 * HID + u) * D_IN + d];
          w.z = Wih[(2 * HID + u) * D_IN + d];
          w.w = Wih[(3 * HID + u) * D_IN + d];
        } else {
          w = PWih[d * HID + u];
        }
        ai0 = fmaf(w.x, xv0[d], ai0); af0 = fmaf(w.y, xv0[d], af0);
        ag0 = fmaf(w.z, xv0[d], ag0); ao0 = fmaf(w.w, xv0[d], ao0);
        ai1 = fmaf(w.x, xv1[d], ai1); af1 = fmaf(w.y, xv1[d], af1);
        ag1 = fmaf(w.z, xv1[d], ag1); ao1 = fmaf(w.w, xv1[d], ao1);
      }
    }

    // ---- h @ W_hh.T over this thread's k-half ----
    if (DIRECT) {
      #pragma unroll 16
      for (int kk = 0; kk < 128; ++kk) {
        int k = ks * 128 + kk;
        float4 w;
        w.x = Whh[(0 * HID + u) * HID + k];
        w.y = Whh[(1 * HID + u) * HID + k];
        w.z = Whh[(2 * HID + u) * HID + k];
        w.w = Whh[(3 * HID + u) * HID + k];
        float2 hh = h2p[k * 2 + rp];
        ai0 = fmaf(w.x, hh.x, ai0); af0 = fmaf(w.y, hh.x, af0);
        ag0 = fmaf(w.z, hh.x, ag0); ao0 = fmaf(w.w, hh.x, ao0);
        ai1 = fmaf(w.x, hh.y, ai1); af1 = fmaf(w.y, hh.y, af1);
        ag1 = fmaf(w.z, hh.y, ag1); ao1 = fmaf(w.w, hh.y, ao1);
      }
    } else {
      // 64 k2-iters: 16B coalesced fp16 weights (8 halves = 4 gates x 2 k's),
      // cvt to fp32 in-register, FMA vs fp32 h broadcast from LDS.
      #pragma unroll 8
      for (int kk = 0; kk < 64; ++kk) {
        uint4 w = pwk[(size_t)kk * HID];
        float2 he = h2p[hb + 4 * kk];        // h of unit k=2*(ks*64+kk),   rows 2rp,2rp+1
        float2 ho = h2p[hb + 4 * kk + 2];    // h of unit k=2*(ks*64+kk)+1, rows 2rp,2rp+1
        half2_t wi = __builtin_bit_cast(half2_t, w.x);
        half2_t wf = __builtin_bit_cast(half2_t, w.y);
        half2_t wg = __builtin_bit_cast(half2_t, w.z);
        half2_t wq = __builtin_bit_cast(half2_t, w.w);
        float wi0 = (float)wi[0], wi1 = (float)wi[1];
        float wf0 = (float)wf[0], wf1 = (float)wf[1];
        float wg0 = (float)wg[0], wg1 = (float)wg[1];
        float wq0 = (float)wq[0], wq1 = (float)wq[1];
        ai0 = fmaf(wi0, he.x, ai0); ai1 = fmaf(wi0, he.y, ai1);
        ai0 = fmaf(wi1, ho.x, ai0); ai1 = fmaf(wi1, ho.y, ai1);
        af0 = fmaf(wf0, he.x, af0); af1 = fmaf(wf0, he.y, af1);
        af0 = fmaf(wf1, ho.x, af0); af1 = fmaf(wf1, ho.y, af1);
        ag0 = fmaf(wg0, he.x, ag0); ag1 = fmaf(wg0, he.y, ag1);
        ag0 = fmaf(wg1, ho.x, ag0); ag1 = fmaf(wg1, ho.y, ag1);
        ao0 = fmaf(wq0, he.x, ao0); ao1 = fmaf(wq0, he.y, ao1);
        ao0 = fmaf(wq1, ho.x, ao0); ao1 = fmaf(wq1, ho.y, ao1);
      }
    }

    // ---- write partials [ks][g][r][u] (stride-4B in u -> conflict-free) ----
    part[ks][0][2 * rp + 0][u] = ai0;  part[ks][0][2 * rp + 1][u] = ai1;
    part[ks][1][2 * rp + 0][u] = af0;  part[ks][1][2 * rp + 1][u] = af1;
    part[ks][2][2 * rp + 0][u] = ag0;  part[ks][2][2 * rp + 1][u] = ag1;
    part[ks][3][2 * rp + 0][u] = ao0;  part[ks][3][2 * rp + 1][u] = ao1;

    __syncthreads();   // partials visible; all h reads of this step done

    // ---- reduce + nonlinearity: thread owns (rowR, u) ----
    {
      float gi = part[0][0][rowR][u] + part[1][0][rowR][u];
      float gf = part[0][1][rowR][u] + part[1][1][rowR][u];
      float gg = part[0][2][rowR][u] + part[1][2][rowR][u];
      float go = part[0][3][rowR][u] + part[1][3][rowR][u];
      float iv = sigmoidf_(gi), fv = sigmoidf_(gf);
      float gv = tanhf_(gg),    ov = sigmoidf_(go);
      c_reg = fmaf(fv, c_reg, iv * gv);
      h_reg = ov * tanhf_(c_reg);
      ((float*)h4)[u * 4 + rowR] = h_reg;   // h(step+1), fp32
    }

    __syncthreads();   // h(step+1) visible

    // ---- logits: waves 0..7 -> 8 (row, logit) combos, shuffle-reduce 64 lanes ----
    {
      const int wv = t >> 6;
      if (wv < 8) {
        const int lane = t & 63;
        const int r  = wv >> 1;
        const int lg = wv & 1;
        float partial = 0.f;
        #pragma unroll
        for (int m = 0; m < 4; ++m) {
          int k = lane + 64 * m;
          float4 hv = h4[k];
          float hval = (r == 0) ? hv.x : (r == 1) ? hv.y : (r == 2) ? hv.z : hv.w;
          partial = fmaf(hval, wo[lg * HID + k], partial);
        }
        #pragma unroll
        for (int off = 32; off > 0; off >>= 1)
          partial += __shfl_down(partial, off, 64);
        if (lane == 0) {
          long row = (long)blockIdx.x * 4 + r;
          out[(row * T_STEPS + step) * 2 + lg] = partial + (lg ? b1 : b0);
        }
      }
    }
  }

  // ---- final h_T, c_T (thread owns (rowR,u); coalesced over u) ----
  const long HOFF = (long)B_ROWS * T_STEPS * 2;           // 524288
  const long COFF = HOFF + (long)B_ROWS * HID;            // 655360
  const long grow = (long)blockIdx.x * 4 + rowR;
  out[HOFF + grow * HID + u] = h_reg;
  out[COFF + grow * HID + u] = c_reg;
}

extern "C" void kernel_launch(void* const* d_in, const int* in_sizes, int n_in,
                              void* d_out, int out_size, void* d_ws, size_t ws_size,
                              hipStream_t stream) {
  const float* hist = (const float*)d_in[0];
  const float* Wih  = (const float*)d_in[1];
  const float* Whh  = (const float*)d_in[2];
  const float* Wout = (const float*)d_in[3];
  const float* bout = (const float*)d_in[4];
  float* out = (float*)d_out;

  if (ws_size >= WS_BYTES_NEEDED) {
    uint4* PW2  = (uint4*)d_ws;
    float* PWih = (float*)((char*)d_ws + (size_t)PW2_ENTRIES * 16);
    // (32768 + 8192) / 256 = 160 blocks exactly
    prep_kernel<<<160, 256, 0, stream>>>(Wih, Whh, PW2, PWih);
    lstm_kernel<false><<<B_ROWS / 4, 1024, 0, stream>>>(
        hist, Wih, Whh, Wout, bout, PW2, (const float4*)PWih, out);
  } else {
    lstm_kernel<true><<<B_ROWS / 4, 1024, 0, stream>>>(
        hist, Wih, Whh, Wout, bout, nullptr, nullptr, out);
  }
}

// Round 8
// 4550.661 us; speedup vs baseline: 1.7843x; 1.4617x over previous
//
#include <hip/hip_runtime.h>

// LSTM (bias-free) T=512, B=512, D=8, H=256 + per-step Linear(H,2).
// R8: dedup fix. R7 duplicated the weight stream across rp waves -> 1MB/step/CU
// on the L1<->L2 link (6.8us floor, 13us measured). Now: 128 blocks x 1024 threads,
// thread (u, q=t>>8) computes ALL 4 rows over k-quarter q -> each wave reads a
// DISTINCT 32KB slice; per-CU unique weight traffic 512KB/step (fp16-packed W_hh,
// fp32 cvt+FMA, h stays fp32). Partials in LDS [q][gate][row][u] (64KB), reduce
// owned by (u, row=q). 2 barriers/step.

#define T_STEPS 512
#define B_ROWS  512
#define D_IN    8
#define HID     256

typedef _Float16 half2_t __attribute__((ext_vector_type(2)));

#define PW2_ENTRIES (128 * HID)            // 32768 uint4 (16B each) = 512 KB
#define PWIH_FLOATS (4 * HID * D_IN)       // 8192 floats = 32 KB
#define WS_BYTES_NEEDED ((size_t)PW2_ENTRIES * 16 + (size_t)PWIH_FLOATS * 4)

// PW2[k2*HID+u] = uint4{ half2(Whh[g*H+u][2k2], Whh[g*H+u][2k2+1]) : g=0..3 }
// PWih[d*1024 + u*4 + g] = Wih[g*H+u][d]   (fp32, tiny)
__global__ void prep_kernel(const float* __restrict__ Wih,
                            const float* __restrict__ Whh,
                            uint4* __restrict__ PW2,
                            float* __restrict__ PWih) {
  int p = blockIdx.x * 256 + threadIdx.x;
  if (p < PW2_ENTRIES) {
    int u = p & (HID - 1), k2 = p >> 8;
    unsigned int g[4];
    #pragma unroll
    for (int gi = 0; gi < 4; ++gi) {
      float lo = Whh[(gi * HID + u) * HID + 2 * k2];
      float hi = Whh[(gi * HID + u) * HID + 2 * k2 + 1];
      half2_t hv;
      hv[0] = (_Float16)lo;
      hv[1] = (_Float16)hi;
      g[gi] = __builtin_bit_cast(unsigned int, hv);
    }
    PW2[p] = make_uint4(g[0], g[1], g[2], g[3]);
  } else {
    int q = p - PW2_ENTRIES;
    if (q < PWIH_FLOATS) {
      int gg = q & 3, u = (q >> 2) & (HID - 1), d = q >> 10;
      PWih[q] = Wih[(gg * HID + u) * D_IN + d];
    }
  }
}

__device__ __forceinline__ float sigmoidf_(float x) {
  return 1.f / (1.f + expf(-x));
}
__device__ __forceinline__ float tanhf_(float x) {
  float e = expf(2.f * x);
  return 1.f - 2.f / (e + 1.f);
}

template <bool DIRECT>
__global__ __launch_bounds__(1024, 4)
void lstm_kernel(const float* __restrict__ hist,
                 const float* __restrict__ Wih,
                 const float* __restrict__ Whh,
                 const float* __restrict__ Wout,
                 const float* __restrict__ bout,
                 const uint4* __restrict__ PW2,
                 const float4* __restrict__ PWih,
                 float* __restrict__ out) {
  __shared__ float4 h4[HID];              // fp32 h, [u]{rows 0..3}, 4KB
  __shared__ float  wo[2 * HID];          // W_out staged, 2KB
  __shared__ float  part[4][4][4][HID];   // [q][gate][row][u] partials, 64KB

  const int t = threadIdx.x;
  const int u = t & (HID - 1);
  const int q = t >> 8;                   // k-quarter 0..3; also OWNED row post-reduce

  if (t < 2 * HID) wo[t] = Wout[t];
  if (t < HID) h4[t] = make_float4(0.f, 0.f, 0.f, 0.f);
  float c_reg = 0.f, h_reg = 0.f;
  const float b0 = bout[0], b1 = bout[1];
  __syncthreads();

  const int row0 = blockIdx.x * 4;
  const float4* __restrict__ xp0 = (const float4*)(hist + (long)(row0 + 0) * T_STEPS * D_IN);
  const float4* __restrict__ xp1 = (const float4*)(hist + (long)(row0 + 1) * T_STEPS * D_IN);
  const float4* __restrict__ xp2 = (const float4*)(hist + (long)(row0 + 2) * T_STEPS * D_IN);
  const float4* __restrict__ xp3 = (const float4*)(hist + (long)(row0 + 3) * T_STEPS * D_IN);
  // This thread's weight slice: k2 in [32q, 32q+32)  (k = 2*k2, 2*k2+1)
  const uint4* __restrict__ pwq = DIRECT ? nullptr : (PW2 + (size_t)(32 * q) * HID + u);

  for (int step = 0; step < T_STEPS; ++step) {
    float ai0 = 0.f, ai1 = 0.f, ai2 = 0.f, ai3 = 0.f;
    float af0 = 0.f, af1 = 0.f, af2 = 0.f, af3 = 0.f;
    float ag0 = 0.f, ag1 = 0.f, ag2 = 0.f, ag3 = 0.f;
    float ao0 = 0.f, ao1 = 0.f, ao2 = 0.f, ao3 = 0.f;

    // ---- x @ W_ih.T (D=8, fp32): q==0 waves only, all 4 rows ----
    if (q == 0) {
      float4 a0 = xp0[2 * step], bb0 = xp0[2 * step + 1];
      float4 a1 = xp1[2 * step], bb1 = xp1[2 * step + 1];
      float4 a2 = xp2[2 * step], bb2 = xp2[2 * step + 1];
      float4 a3 = xp3[2 * step], bb3 = xp3[2 * step + 1];
      float x0[D_IN] = {a0.x, a0.y, a0.z, a0.w, bb0.x, bb0.y, bb0.z, bb0.w};
      float x1[D_IN] = {a1.x, a1.y, a1.z, a1.w, bb1.x, bb1.y, bb1.z, bb1.w};
      float x2[D_IN] = {a2.x, a2.y, a2.z, a2.w, bb2.x, bb2.y, bb2.z, bb2.w};
      float x3[D_IN] = {a3.x, a3.y, a3.z, a3.w, bb3.x, bb3.y, bb3.z, bb3.w};
      #pragma unroll
      for (int d = 0; d < D_IN; ++d) {
        float4 w;
        if (DIRECT) {
          w.x = Wih[(0 * HID + u) * D_IN + d];
          w.y = Wih[(1 * HID + u) * D_IN + d];
          w.z = Wih[(2 * HID + u) * D_IN + d];
          w.w = Wih[(3 * HID + u) * D_IN + d];
        } else {
          w = PWih[d * HID + u];
        }
        ai0 = fmaf(w.x, x0[d], ai0); af0 = fmaf(w.y, x0[d], af0);
        ag0 = fmaf(w.z, x0[d], ag0); ao0 = fmaf(w.w, x0[d], ao0);
        ai1 = fmaf(w.x, x1[d], ai1); af1 = fmaf(w.y, x1[d], af1);
        ag1 = fmaf(w.z, x1[d], ag1); ao1 = fmaf(w.w, x1[d], ao1);
        ai2 = fmaf(w.x, x2[d], ai2); af2 = fmaf(w.y, x2[d], af2);
        ag2 = fmaf(w.z, x2[d], ag2); ao2 = fmaf(w.w, x2[d], ao2);
        ai3 = fmaf(w.x, x3[d], ai3); af3 = fmaf(w.y, x3[d], af3);
        ag3 = fmaf(w.z, x3[d], ag3); ao3 = fmaf(w.w, x3[d], ao3);
      }
    }

    // ---- h @ W_hh.T over k-quarter q: 32 iters, each = 1 coalesced 16B weight
    //      load (4 gates x 2 k's, fp16) + 2 broadcast float4 h reads + 32 FMA ----
    #pragma unroll 8
    for (int kk = 0; kk < 32; ++kk) {
      float wiA, wiB, wfA, wfB, wgA, wgB, woA, woB;
      if (DIRECT) {
        int k = 2 * (32 * q + kk);
        wiA = Whh[(0 * HID + u) * HID + k]; wiB = Whh[(0 * HID + u) * HID + k + 1];
        wfA = Whh[(1 * HID + u) * HID + k]; wfB = Whh[(1 * HID + u) * HID + k + 1];
        wgA = Whh[(2 * HID + u) * HID + k]; wgB = Whh[(2 * HID + u) * HID + k + 1];
        woA = Whh[(3 * HID + u) * HID + k]; woB = Whh[(3 * HID + u) * HID + k + 1];
      } else {
        uint4 w = pwq[(size_t)kk * HID];
        half2_t wi = __builtin_bit_cast(half2_t, w.x);
        half2_t wf = __builtin_bit_cast(half2_t, w.y);
        half2_t wg = __builtin_bit_cast(half2_t, w.z);
        half2_t wq_ = __builtin_bit_cast(half2_t, w.w);
        wiA = (float)wi[0]; wiB = (float)wi[1];
        wfA = (float)wf[0]; wfB = (float)wf[1];
        wgA = (float)wg[0]; wgB = (float)wg[1];
        woA = (float)wq_[0]; woB = (float)wq_[1];
      }
      float4 hA = h4[(32 * q + kk) * 2];      // unit 2k2:   h of rows 0..3 (broadcast)
      float4 hB = h4[(32 * q + kk) * 2 + 1];  // unit 2k2+1
      ai0 = fmaf(wiA, hA.x, ai0); ai1 = fmaf(wiA, hA.y, ai1);
      ai2 = fmaf(wiA, hA.z, ai2); ai3 = fmaf(wiA, hA.w, ai3);
      ai0 = fmaf(wiB, hB.x, ai0); ai1 = fmaf(wiB, hB.y, ai1);
      ai2 = fmaf(wiB, hB.z, ai2); ai3 = fmaf(wiB, hB.w, ai3);
      af0 = fmaf(wfA, hA.x, af0); af1 = fmaf(wfA, hA.y, af1);
      af2 = fmaf(wfA, hA.z, af2); af3 = fmaf(wfA, hA.w, af3);
      af0 = fmaf(wfB, hB.x, af0); af1 = fmaf(wfB, hB.y, af1);
      af2 = fmaf(wfB, hB.z, af2); af3 = fmaf(wfB, hB.w, af3);
      ag0 = fmaf(wgA, hA.x, ag0); ag1 = fmaf(wgA, hA.y, ag1);
      ag2 = fmaf(wgA, hA.z, ag2); ag3 = fmaf(wgA, hA.w, ag3);
      ag0 = fmaf(wgB, hB.x, ag0); ag1 = fmaf(wgB, hB.y, ag1);
      ag2 = fmaf(wgB, hB.z, ag2); ag3 = fmaf(wgB, hB.w, ag3);
      ao0 = fmaf(woA, hA.x, ao0); ao1 = fmaf(woA, hA.y, ao1);
      ao2 = fmaf(woA, hA.z, ao2); ao3 = fmaf(woA, hA.w, ao3);
      ao0 = fmaf(woB, hB.x, ao0); ao1 = fmaf(woB, hB.y, ao1);
      ao2 = fmaf(woB, hB.z, ao2); ao3 = fmaf(woB, hB.w, ao3);
    }

    // ---- write partials [q][gate][row][u] (stride-4B in u -> conflict-free) ----
    part[q][0][0][u] = ai0; part[q][0][1][u] = ai1; part[q][0][2][u] = ai2; part[q][0][3][u] = ai3;
    part[q][1][0][u] = af0; part[q][1][1][u] = af1; part[q][1][2][u] = af2; part[q][1][3][u] = af3;
    part[q][2][0][u] = ag0; part[q][2][1][u] = ag1; part[q][2][2][u] = ag2; part[q][2][3][u] = ag3;
    part[q][3][0][u] = ao0; part[q][3][1][u] = ao1; part[q][3][2][u] = ao2; part[q][3][3][u] = ao3;

    __syncthreads();   // partials visible; all h4 reads of this step done

    // ---- reduce over 4 quarters + nonlinearity: thread owns (row=q, u) ----
    {
      float gi = part[0][0][q][u] + part[1][0][q][u] + part[2][0][q][u] + part[3][0][q][u];
      float gf = part[0][1][q][u] + part[1][1][q][u] + part[2][1][q][u] + part[3][1][q][u];
      float gg = part[0][2][q][u] + part[1][2][q][u] + part[2][2][q][u] + part[3][2][q][u];
      float go = part[0][3][q][u] + part[1][3][q][u] + part[2][3][q][u] + part[3][3][q][u];
      float iv = sigmoidf_(gi), fv = sigmoidf_(gf);
      float gv = tanhf_(gg),    ov = sigmoidf_(go);
      c_reg = fmaf(fv, c_reg, iv * gv);
      h_reg = ov * tanhf_(c_reg);
      ((float*)h4)[u * 4 + q] = h_reg;   // h(step+1), fp32
    }

    __syncthreads();   // h(step+1) visible

    // ---- logits: waves 0..7 -> 8 (row, logit) combos, shuffle-reduce 64 lanes ----
    {
      const int wv = t >> 6;
      if (wv < 8) {
        const int lane = t & 63;
        const int r  = wv >> 1;
        const int lg = wv & 1;
        float partial = 0.f;
        #pragma unroll
        for (int m = 0; m < 4; ++m) {
          int k = lane + 64 * m;
          float4 hv = h4[k];
          float hval = (r == 0) ? hv.x : (r == 1) ? hv.y : (r == 2) ? hv.z : hv.w;
          partial = fmaf(hval, wo[lg * HID + k], partial);
        }
        #pragma unroll
        for (int off = 32; off > 0; off >>= 1)
          partial += __shfl_down(partial, off, 64);
        if (lane == 0) {
          long row = (long)row0 + r;
          out[(row * T_STEPS + step) * 2 + lg] = partial + (lg ? b1 : b0);
        }
      }
    }
  }

  // ---- final h_T, c_T (thread owns (row=q, u); coalesced over u) ----
  const long HOFF = (long)B_ROWS * T_STEPS * 2;           // 524288
  const long COFF = HOFF + (long)B_ROWS * HID;            // 655360
  const long grow = (long)row0 + q;
  out[HOFF + grow * HID + u] = h_reg;
  out[COFF + grow * HID + u] = c_reg;
}

extern "C" void kernel_launch(void* const* d_in, const int* in_sizes, int n_in,
                              void* d_out, int out_size, void* d_ws, size_t ws_size,
                              hipStream_t stream) {
  const float* hist = (const float*)d_in[0];
  const float* Wih  = (const float*)d_in[1];
  const float* Whh  = (const float*)d_in[2];
  const float* Wout = (const float*)d_in[3];
  const float* bout = (const float*)d_in[4];
  float* out = (float*)d_out;

  if (ws_size >= WS_BYTES_NEEDED) {
    uint4* PW2  = (uint4*)d_ws;
    float* PWih = (float*)((char*)d_ws + (size_t)PW2_ENTRIES * 16);
    // (32768 + 8192) / 256 = 160 blocks exactly
    prep_kernel<<<160, 256, 0, stream>>>(Wih, Whh, PW2, PWih);
    lstm_kernel<false><<<B_ROWS / 4, 1024, 0, stream>>>(
        hist, Wih, Whh, Wout, bout, PW2, (const float4*)PWih, out);
  } else {
    lstm_kernel<true><<<B_ROWS / 4, 1024, 0, stream>>>(
        hist, Wih, Whh, Wout, bout, nullptr, nullptr, out);
  }
}

// Round 11
// 3311.566 us; speedup vs baseline: 2.4520x; 1.3742x over previous
//
#include <hip/hip_runtime.h>

// LSTM (bias-free) T=512, B=512, D=8, H=256 + per-step Linear(H,2).
// R11 (= R10/R9 resubmit; never ran due to GPU timeouts): dedup 4-way k-split +
// fp16 W_hh + v_dot2_f32_f16 gate GEMM. k-loop iter: 1 coalesced uint4 weight load
// (4 gates x 2 k's fp16) + 1 wave-uniform uint4 h16 read (4 rows x 2 k's) + 16 dot2
// (fp32 acc). h fp32 in h4 (logits/state) + fp16 shadow h16 [k2][row][half] for dot2.
// Partials LDS [q][gate][row][u]; 2 barriers/step.

#define T_STEPS 512
#define B_ROWS  512
#define D_IN    8
#define HID     256

typedef _Float16 half2_t __attribute__((ext_vector_type(2)));

#if defined(__has_builtin)
#  if __has_builtin(__builtin_amdgcn_fdot2)
#    define HAVE_FDOT2 1
#  endif
#endif
#ifndef HAVE_FDOT2
#  define HAVE_FDOT2 0
#endif

#define PW2_ENTRIES (128 * HID)            // 32768 uint4 (16B each) = 512 KB
#define PWIH_FLOATS (4 * HID * D_IN)       // 8192 floats = 32 KB
#define WS_BYTES_NEEDED ((size_t)PW2_ENTRIES * 16 + (size_t)PWIH_FLOATS * 4)

// PW2[k2*HID+u] = uint4{ half2(Whh[g*H+u][2k2], Whh[g*H+u][2k2+1]) : g=0..3 }
// PWih[d*1024 + u*4 + g] = Wih[g*H+u][d]   (fp32, tiny)
__global__ void prep_kernel(const float* __restrict__ Wih,
                            const float* __restrict__ Whh,
                            uint4* __restrict__ PW2,
                            float* __restrict__ PWih) {
  int p = blockIdx.x * 256 + threadIdx.x;
  if (p < PW2_ENTRIES) {
    int u = p & (HID - 1), k2 = p >> 8;
    unsigned int g[4];
    #pragma unroll
    for (int gi = 0; gi < 4; ++gi) {
      float lo = Whh[(gi * HID + u) * HID + 2 * k2];
      float hi = Whh[(gi * HID + u) * HID + 2 * k2 + 1];
      half2_t hv;
      hv[0] = (_Float16)lo;
      hv[1] = (_Float16)hi;
      g[gi] = __builtin_bit_cast(unsigned int, hv);
    }
    PW2[p] = make_uint4(g[0], g[1], g[2], g[3]);
  } else {
    int q = p - PW2_ENTRIES;
    if (q < PWIH_FLOATS) {
      int gg = q & 3, u = (q >> 2) & (HID - 1), d = q >> 10;
      PWih[q] = Wih[(gg * HID + u) * D_IN + d];
    }
  }
}

__device__ __forceinline__ float sigmoidf_(float x) {
  return 1.f / (1.f + expf(-x));
}
__device__ __forceinline__ float tanhf_(float x) {
  float e = expf(2.f * x);
  return 1.f - 2.f / (e + 1.f);
}

__device__ __forceinline__ float dot2f(unsigned int wbits, unsigned int hbits, float acc) {
  half2_t w = __builtin_bit_cast(half2_t, wbits);
  half2_t h = __builtin_bit_cast(half2_t, hbits);
#if HAVE_FDOT2
  return __builtin_amdgcn_fdot2(w, h, acc, false);
#else
  acc = fmaf((float)w[0], (float)h[0], acc);
  return fmaf((float)w[1], (float)h[1], acc);
#endif
}

template <bool DIRECT>
__global__ __launch_bounds__(1024, 4)
void lstm_kernel(const float* __restrict__ hist,
                 const float* __restrict__ Wih,
                 const float* __restrict__ Whh,
                 const float* __restrict__ Wout,
                 const float* __restrict__ bout,
                 const uint4* __restrict__ PW2,
                 const float4* __restrict__ PWih,
                 float* __restrict__ out) {
  __shared__ float4   h4[HID];              // fp32 h, [u]{rows 0..3}, 4KB
  __shared__ _Float16 h16[HID / 2][4][2];   // fp16 h, [k2][row][half], 2KB
  __shared__ float    wo[2 * HID];          // W_out staged, 2KB
  __shared__ float    part[4][4][4][HID];   // [q][gate][row][u] partials, 64KB

  const int t = threadIdx.x;
  const int u = t & (HID - 1);
  const int q = t >> 8;                     // k-quarter 0..3; also OWNED row post-reduce

  if (t < 2 * HID) wo[t] = Wout[t];
  if (t < HID) h4[t] = make_float4(0.f, 0.f, 0.f, 0.f);
  ((_Float16*)h16)[t] = (_Float16)0.f;      // 1024 halves = blockDim exactly
  float c_reg = 0.f, h_reg = 0.f;
  const float b0 = bout[0], b1 = bout[1];
  __syncthreads();

  const int row0 = blockIdx.x * 4;
  const float4* __restrict__ xp0 = (const float4*)(hist + (long)(row0 + 0) * T_STEPS * D_IN);
  const float4* __restrict__ xp1 = (const float4*)(hist + (long)(row0 + 1) * T_STEPS * D_IN);
  const float4* __restrict__ xp2 = (const float4*)(hist + (long)(row0 + 2) * T_STEPS * D_IN);
  const float4* __restrict__ xp3 = (const float4*)(hist + (long)(row0 + 3) * T_STEPS * D_IN);
  // This thread's weight slice: k2 in [32q, 32q+32)  (k = 2*k2, 2*k2+1)
  const uint4* __restrict__ pwq = DIRECT ? nullptr : (PW2 + (size_t)(32 * q) * HID + u);
  const uint4* __restrict__ h16q = (const uint4*)h16;   // [k2] -> {row0,row1,row2,row3} pairs

  for (int step = 0; step < T_STEPS; ++step) {
    float ai0 = 0.f, ai1 = 0.f, ai2 = 0.f, ai3 = 0.f;
    float af0 = 0.f, af1 = 0.f, af2 = 0.f, af3 = 0.f;
    float ag0 = 0.f, ag1 = 0.f, ag2 = 0.f, ag3 = 0.f;
    float ao0 = 0.f, ao1 = 0.f, ao2 = 0.f, ao3 = 0.f;

    // ---- x @ W_ih.T (D=8, fp32): q==0 waves only, all 4 rows ----
    if (q == 0) {
      float4 a0 = xp0[2 * step], bb0 = xp0[2 * step + 1];
      float4 a1 = xp1[2 * step], bb1 = xp1[2 * step + 1];
      float4 a2 = xp2[2 * step], bb2 = xp2[2 * step + 1];
      float4 a3 = xp3[2 * step], bb3 = xp3[2 * step + 1];
      float x0[D_IN] = {a0.x, a0.y, a0.z, a0.w, bb0.x, bb0.y, bb0.z, bb0.w};
      float x1[D_IN] = {a1.x, a1.y, a1.z, a1.w, bb1.x, bb1.y, bb1.z, bb1.w};
      float x2[D_IN] = {a2.x, a2.y, a2.z, a2.w, bb2.x, bb2.y, bb2.z, bb2.w};
      float x3[D_IN] = {a3.x, a3.y, a3.z, a3.w, bb3.x, bb3.y, bb3.z, bb3.w};
      #pragma unroll
      for (int d = 0; d < D_IN; ++d) {
        float4 w;
        if (DIRECT) {
          w.x = Wih[(0 * HID + u) * D_IN + d];
          w.y = Wih[(1 * HID + u) * D_IN + d];
          w.z = Wih[(2 * HID + u) * D_IN + d];
          w.w = Wih[(3 * HID + u) * D_IN + d];
        } else {
          w = PWih[d * HID + u];
        }
        ai0 = fmaf(w.x, x0[d], ai0); af0 = fmaf(w.y, x0[d], af0);
        ag0 = fmaf(w.z, x0[d], ag0); ao0 = fmaf(w.w, x0[d], ao0);
        ai1 = fmaf(w.x, x1[d], ai1); af1 = fmaf(w.y, x1[d], af1);
        ag1 = fmaf(w.z, x1[d], ag1); ao1 = fmaf(w.w, x1[d], ao1);
        ai2 = fmaf(w.x, x2[d], ai2); af2 = fmaf(w.y, x2[d], af2);
        ag2 = fmaf(w.z, x2[d], ag2); ao2 = fmaf(w.w, x2[d], ao2);
        ai3 = fmaf(w.x, x3[d], ai3); af3 = fmaf(w.y, x3[d], af3);
        ag3 = fmaf(w.z, x3[d], ag3); ao3 = fmaf(w.w, x3[d], ao3);
      }
    }

    // ---- h @ W_hh.T over k-quarter q ----
    if (DIRECT) {
      #pragma unroll 8
      for (int kk = 0; kk < 32; ++kk) {
        int k = 2 * (32 * q + kk);
        float wiA = Whh[(0 * HID + u) * HID + k], wiB = Whh[(0 * HID + u) * HID + k + 1];
        float wfA = Whh[(1 * HID + u) * HID + k], wfB = Whh[(1 * HID + u) * HID + k + 1];
        float wgA = Whh[(2 * HID + u) * HID + k], wgB = Whh[(2 * HID + u) * HID + k + 1];
        float woA = Whh[(3 * HID + u) * HID + k], woB = Whh[(3 * HID + u) * HID + k + 1];
        float4 hA = h4[k];
        float4 hB = h4[k + 1];
        ai0 = fmaf(wiA, hA.x, ai0); ai1 = fmaf(wiA, hA.y, ai1);
        ai2 = fmaf(wiA, hA.z, ai2); ai3 = fmaf(wiA, hA.w, ai3);
        ai0 = fmaf(wiB, hB.x, ai0); ai1 = fmaf(wiB, hB.y, ai1);
        ai2 = fmaf(wiB, hB.z, ai2); ai3 = fmaf(wiB, hB.w, ai3);
        af0 = fmaf(wfA, hA.x, af0); af1 = fmaf(wfA, hA.y, af1);
        af2 = fmaf(wfA, hA.z, af2); af3 = fmaf(wfA, hA.w, af3);
        af0 = fmaf(wfB, hB.x, af0); af1 = fmaf(wfB, hB.y, af1);
        af2 = fmaf(wfB, hB.z, af2); af3 = fmaf(wfB, hB.w, af3);
        ag0 = fmaf(wgA, hA.x, ag0); ag1 = fmaf(wgA, hA.y, ag1);
        ag2 = fmaf(wgA, hA.z, ag2); ag3 = fmaf(wgA, hA.w, ag3);
        ag0 = fmaf(wgB, hB.x, ag0); ag1 = fmaf(wgB, hB.y, ag1);
        ag2 = fmaf(wgB, hB.z, ag2); ag3 = fmaf(wgB, hB.w, ag3);
        ao0 = fmaf(woA, hA.x, ao0); ao1 = fmaf(woA, hA.y, ao1);
        ao2 = fmaf(woA, hA.z, ao2); ao3 = fmaf(woA, hA.w, ao3);
        ao0 = fmaf(woB, hB.x, ao0); ao1 = fmaf(woB, hB.y, ao1);
        ao2 = fmaf(woB, hB.z, ao2); ao3 = fmaf(woB, hB.w, ao3);
      }
    } else {
      // 32 iters: 1 uint4 weight load + 1 wave-uniform uint4 h16 read + 16 dot2
      #pragma unroll 8
      for (int kk = 0; kk < 32; ++kk) {
        uint4 w  = pwq[(size_t)kk * HID];
        uint4 hp = h16q[32 * q + kk];     // {rows 0..3} x {units 2k2, 2k2+1}
        ai0 = dot2f(w.x, hp.x, ai0); ai1 = dot2f(w.x, hp.y, ai1);
        ai2 = dot2f(w.x, hp.z, ai2); ai3 = dot2f(w.x, hp.w, ai3);
        af0 = dot2f(w.y, hp.x, af0); af1 = dot2f(w.y, hp.y, af1);
        af2 = dot2f(w.y, hp.z, af2); af3 = dot2f(w.y, hp.w, af3);
        ag0 = dot2f(w.z, hp.x, ag0); ag1 = dot2f(w.z, hp.y, ag1);
        ag2 = dot2f(w.z, hp.z, ag2); ag3 = dot2f(w.z, hp.w, ag3);
        ao0 = dot2f(w.w, hp.x, ao0); ao1 = dot2f(w.w, hp.y, ao1);
        ao2 = dot2f(w.w, hp.z, ao2); ao3 = dot2f(w.w, hp.w, ao3);
      }
    }

    // ---- write partials [q][gate][row][u] (stride-4B in u -> conflict-free) ----
    part[q][0][0][u] = ai0; part[q][0][1][u] = ai1; part[q][0][2][u] = ai2; part[q][0][3][u] = ai3;
    part[q][1][0][u] = af0; part[q][1][1][u] = af1; part[q][1][2][u] = af2; part[q][1][3][u] = af3;
    part[q][2][0][u] = ag0; part[q][2][1][u] = ag1; part[q][2][2][u] = ag2; part[q][2][3][u] = ag3;
    part[q][3][0][u] = ao0; part[q][3][1][u] = ao1; part[q][3][2][u] = ao2; part[q][3][3][u] = ao3;

    __syncthreads();   // partials visible; all h reads of this step done

    // ---- reduce over 4 quarters + nonlinearity: thread owns (row=q, u) ----
    {
      float gi = part[0][0][q][u] + part[1][0][q][u] + part[2][0][q][u] + part[3][0][q][u];
      float gf = part[0][1][q][u] + part[1][1][q][u] + part[2][1][q][u] + part[3][1][q][u];
      float gg = part[0][2][q][u] + part[1][2][q][u] + part[2][2][q][u] + part[3][2][q][u];
      float go = part[0][3][q][u] + part[1][3][q][u] + part[2][3][q][u] + part[3][3][q][u];
      float iv = sigmoidf_(gi), fv = sigmoidf_(gf);
      float gv = tanhf_(gg),    ov = sigmoidf_(go);
      c_reg = fmaf(fv, c_reg, iv * gv);
      h_reg = ov * tanhf_(c_reg);
      ((float*)h4)[u * 4 + q] = h_reg;            // fp32 h(step+1)
      h16[u >> 1][q][u & 1] = (_Float16)h_reg;    // fp16 shadow (dot2 operand)
    }

    __syncthreads();   // h(step+1) visible

    // ---- logits: waves 0..7 -> 8 (row, logit) combos, shuffle-reduce 64 lanes ----
    {
      const int wv = t >> 6;
      if (wv < 8) {
        const int lane = t & 63;
        const int r  = wv >> 1;
        const int lg = wv & 1;
        float partial = 0.f;
        #pragma unroll
        for (int m = 0; m < 4; ++m) {
          int k = lane + 64 * m;
          float4 hv = h4[k];
          float hval = (r == 0) ? hv.x : (r == 1) ? hv.y : (r == 2) ? hv.z : hv.w;
          partial = fmaf(hval, wo[lg * HID + k], partial);
        }
        #pragma unroll
        for (int off = 32; off > 0; off >>= 1)
          partial += __shfl_down(partial, off, 64);
        if (lane == 0) {
          long row = (long)row0 + r;
          out[(row * T_STEPS + step) * 2 + lg] = partial + (lg ? b1 : b0);
        }
      }
    }
  }

  // ---- final h_T, c_T (thread owns (row=q, u); coalesced over u) ----
  const long HOFF = (long)B_ROWS * T_STEPS * 2;           // 524288
  const long COFF = HOFF + (long)B_ROWS * HID;            // 655360
  const long grow = (long)row0 + q;
  out[HOFF + grow * HID + u] = h_reg;
  out[COFF + grow * HID + u] = c_reg;
}

extern "C" void kernel_launch(void* const* d_in, const int* in_sizes, int n_in,
                              void* d_out, int out_size, void* d_ws, size_t ws_size,
                              hipStream_t stream) {
  const float* hist = (const float*)d_in[0];
  const float* Wih  = (const float*)d_in[1];
  const float* Whh  = (const float*)d_in[2];
  const float* Wout = (const float*)d_in[3];
  const float* bout = (const float*)d_in[4];
  float* out = (float*)d_out;

  if (ws_size >= WS_BYTES_NEEDED) {
    uint4* PW2  = (uint4*)d_ws;
    float* PWih = (float*)((char*)d_ws + (size_t)PW2_ENTRIES * 16);
    // (32768 + 8192) / 256 = 160 blocks exactly
    prep_kernel<<<160, 256, 0, stream>>>(Wih, Whh, PW2, PWih);
    lstm_kernel<false><<<B_ROWS / 4, 1024, 0, stream>>>(
        hist, Wih, Whh, Wout, bout, PW2, (const float4*)PWih, out);
  } else {
    lstm_kernel<true><<<B_ROWS / 4, 1024, 0, stream>>>(
        hist, Wih, Whh, Wout, bout, nullptr, nullptr, out);
  }
}